// Round 1
// baseline (446.839 us; speedup 1.0000x reference)
//
#include <hip/hip_runtime.h>

// MTSiLU: out = (w[c, bin(x)] * x + b[c, bin(x)]) * sigmoid(x)
// x: [B=16, C=64, H=256, W=256] fp32; weight/bias: [64, 20] fp32.
// Element-wise, HBM-bound: 537 MB total traffic -> ~85 us floor @ 6.3 TB/s.
//
// R1 changes vs 434.6us baseline:
//  - grid 16384 -> 2048 blocks (8 wg/CU): table-preload prologue amortized
//    over 32 iterations/thread instead of 4 (payload/block 16 KB -> 128 KB).
//  - float4 table preload (2 iters) instead of 10 scalar loads/thread.
//  - unroll x4 grid-stride: 4 outstanding float4 loads per thread.
//  - __float2int_rd + v_rcp_f32 sigmoid (error << absmax slack).
// LDS gather is conflict-free by construction (20-word window < 32 banks).

#define MT_C 64
#define MT_BINS 20
#define MT_TABLE (MT_C * MT_BINS)   // 1280 floats per table
#define NTHREADS 256
#define NBLOCKS 2048                // 8 workgroups/CU on 256 CUs
#define UNROLL 4

__device__ __forceinline__ float mtsilu_elem(float xk,
                                             const float* __restrict__ swc,
                                             const float* __restrict__ sbc) {
    int idx = __float2int_rd(xk * 10.0f) + (MT_BINS / 2);   // v_cvt_flr_i32_f32
    idx = idx < 0 ? 0 : (idx > MT_BINS - 1 ? MT_BINS - 1 : idx);
    float wv = swc[idx];
    float bv = sbc[idx];
    // sigmoid via v_exp + v_rcp approx (~1 ulp); avoids IEEE div sequence.
    float s = __builtin_amdgcn_rcpf(1.0f + __expf(-xk));
    return fmaf(wv, xk, bv) * s;
}

__global__ __launch_bounds__(NTHREADS, 8) void mtsilu_kernel(
    const float4* __restrict__ x,
    const float* __restrict__ weight,
    const float* __restrict__ bias,
    float4* __restrict__ out,
    int nvec)
{
    __shared__ float sw[MT_TABLE];
    __shared__ float sb[MT_TABLE];
    {
        // 1280 floats = 320 float4 per table; 256 threads -> 2 iterations.
        const float4* w4 = (const float4*)weight;
        const float4* b4 = (const float4*)bias;
        float4* sw4 = (float4*)sw;
        float4* sb4 = (float4*)sb;
        for (int i = threadIdx.x; i < MT_TABLE / 4; i += NTHREADS) {
            sw4[i] = w4[i];
            sb4[i] = b4[i];
        }
    }
    __syncthreads();

    const int stride = gridDim.x * NTHREADS;
    int i = (int)blockIdx.x * NTHREADS + (int)threadIdx.x;

    // Main loop: batch UNROLL loads (4 outstanding 16B loads/thread),
    // then compute + store each.
    for (; i + (UNROLL - 1) * stride < nvec; i += UNROLL * stride) {
        float4 v[UNROLL];
        int cb[UNROLL];
        #pragma unroll
        for (int u = 0; u < UNROLL; ++u) {
            int j = i + u * stride;
            v[u] = x[j];
            // channel is wave-uniform: 64-lane window never straddles a
            // 16384-float4 channel plane -> hoist to SGPR.
            int jc = __builtin_amdgcn_readfirstlane(j);
            cb[u] = ((jc >> 14) & (MT_C - 1)) * MT_BINS;
        }
        #pragma unroll
        for (int u = 0; u < UNROLL; ++u) {
            const float* swc = sw + cb[u];
            const float* sbc = sb + cb[u];
            float4 o;
            o.x = mtsilu_elem(v[u].x, swc, sbc);
            o.y = mtsilu_elem(v[u].y, swc, sbc);
            o.z = mtsilu_elem(v[u].z, swc, sbc);
            o.w = mtsilu_elem(v[u].w, swc, sbc);
            out[i + u * stride] = o;
        }
    }
    // Tail (empty for the bench shape: 16777216 = 32 * 2048 * 256 / 1... exact)
    for (; i < nvec; i += stride) {
        float4 v = x[i];
        const int cbase = ((i >> 14) & (MT_C - 1)) * MT_BINS;
        float4 o;
        o.x = mtsilu_elem(v.x, sw + cbase, sb + cbase);
        o.y = mtsilu_elem(v.y, sw + cbase, sb + cbase);
        o.z = mtsilu_elem(v.z, sw + cbase, sb + cbase);
        o.w = mtsilu_elem(v.w, sw + cbase, sb + cbase);
        out[i] = o;
    }
}

extern "C" void kernel_launch(void* const* d_in, const int* in_sizes, int n_in,
                              void* d_out, int out_size, void* d_ws, size_t ws_size,
                              hipStream_t stream) {
    const float4* x      = (const float4*)d_in[0];
    const float*  weight = (const float*)d_in[1];
    const float*  bias   = (const float*)d_in[2];
    float4*       out    = (float4*)d_out;

    const int n    = in_sizes[0];        // 16*64*256*256 = 67108864
    const int nvec = n / 4;              // 16777216 float4

    mtsilu_kernel<<<NBLOCKS, NTHREADS, 0, stream>>>(x, weight, bias, out, nvec);
}

// Round 2
// 429.707 us; speedup vs baseline: 1.0399x; 1.0399x over previous
//
#include <hip/hip_runtime.h>

// MTSiLU: out = (w[c, bin(x)] * x + b[c, bin(x)]) * sigmoid(x)
// x: [B=16, C=64, H=256, W=256] fp32; weight/bias: [64, 20] fp32.
// HBM-bound: 537 MB total traffic -> ~85 us floor @ 6.3 TB/s achievable.
//
// R2 structure: one block = one contiguous quarter of one (b,c) plane.
//  - table preload shrinks 10 KB -> 160 B (20 float2, loaded by 20 threads)
//  - w,b fetched together via single ds_read_b64 (<=20 distinct addrs in a
//    64-lane read -> per-bank single address + broadcast, conflict-free)
//  - zero per-element channel math (channel fixed per block)
//  - contiguous 64 KB in / 64 KB out per block, fully static unrolled loop
//  - no forced waves/EU cap (R1's __launch_bounds__(256,8) VGPR ceiling
//    suspected regression source)
// idx math kept EXACTLY as reference (floor(x*10)+10 in fp32, no fma fusion:
// single-rounded x*10+10 can flip boundary bins vs round(x*10)+10).

#define MT_BINS 20
#define NTHREADS 256
#define PLANE_VEC 16384                 // float4 per (b,c) plane = 256*256/4
#define BPP 4                           // blocks per plane
#define CHUNK (PLANE_VEC / BPP)         // 4096 float4 per block
#define ITERS (CHUNK / NTHREADS)        // 16
#define UNROLL 4

__device__ __forceinline__ float mtsilu_elem(float xk,
                                             const float2* __restrict__ swb) {
    int idx = __float2int_rd(xk * 10.0f) + (MT_BINS / 2);  // == floor(x*10)+10
    idx = idx < 0 ? 0 : (idx > MT_BINS - 1 ? MT_BINS - 1 : idx);
    float2 t = swb[idx];                                   // one ds_read_b64
    float s = __builtin_amdgcn_rcpf(1.0f + __expf(-xk));   // ~1ulp sigmoid
    return fmaf(t.x, xk, t.y) * s;
}

__global__ __launch_bounds__(NTHREADS) void mtsilu_kernel(
    const float4* __restrict__ x,
    const float* __restrict__ weight,
    const float* __restrict__ bias,
    float4* __restrict__ out,
    int nvec)
{
    __shared__ float2 swb[MT_BINS];
    // CHUNK divides PLANE_VEC exactly -> every block lives in one channel.
    const int c = ((int)blockIdx.x / BPP) & 63;
    if (threadIdx.x < MT_BINS) {
        swb[threadIdx.x] = make_float2(weight[c * MT_BINS + threadIdx.x],
                                       bias[c * MT_BINS + threadIdx.x]);
    }
    __syncthreads();

    const int base = (int)blockIdx.x * CHUNK + (int)threadIdx.x;

    if ((int)blockIdx.x != (int)gridDim.x - 1 || base + (ITERS - 1) * NTHREADS < nvec) {
        // Fast path: fully in-bounds, static unroll.
        #pragma unroll
        for (int it = 0; it < ITERS; it += UNROLL) {
            float4 v[UNROLL];
            #pragma unroll
            for (int u = 0; u < UNROLL; ++u)
                v[u] = x[base + (it + u) * NTHREADS];
            #pragma unroll
            for (int u = 0; u < UNROLL; ++u) {
                float4 o;
                o.x = mtsilu_elem(v[u].x, swb);
                o.y = mtsilu_elem(v[u].y, swb);
                o.z = mtsilu_elem(v[u].z, swb);
                o.w = mtsilu_elem(v[u].w, swb);
                out[base + (it + u) * NTHREADS] = o;
            }
        }
    } else {
        // Guarded tail (unused for the bench shape: 16777216 % 4096 == 0).
        for (int it = 0; it < ITERS; ++it) {
            int j = base + it * NTHREADS;
            if (j < nvec) {
                float4 v = x[j];
                float4 o;
                o.x = mtsilu_elem(v.x, swb);
                o.y = mtsilu_elem(v.y, swb);
                o.z = mtsilu_elem(v.z, swb);
                o.w = mtsilu_elem(v.w, swb);
                out[j] = o;
            }
        }
    }
}

extern "C" void kernel_launch(void* const* d_in, const int* in_sizes, int n_in,
                              void* d_out, int out_size, void* d_ws, size_t ws_size,
                              hipStream_t stream) {
    const float4* x      = (const float4*)d_in[0];
    const float*  weight = (const float*)d_in[1];
    const float*  bias   = (const float*)d_in[2];
    float4*       out    = (float4*)d_out;

    const int n    = in_sizes[0];        // 16*64*256*256 = 67108864 elements
    const int nvec = n / 4;              // 16777216 float4

    const int grid = (nvec + CHUNK - 1) / CHUNK;   // 4096 -> 16 wg/CU
    mtsilu_kernel<<<grid, NTHREADS, 0, stream>>>(x, weight, bias, out, nvec);
}

// Round 4
// 424.456 us; speedup vs baseline: 1.0527x; 1.0124x over previous
//
#include <hip/hip_runtime.h>

// MTSiLU: out = (w[c, bin(x)] * x + b[c, bin(x)]) * sigmoid(x)
// x: [B=16, C=64, H=256, W=256] fp32; weight/bias: [64, 20] fp32.
// HBM-bound: 537 MB total traffic; m13 float4-copy ceiling 6.29 TB/s -> 85 us floor.
//
// R4 = R3 with the compile fix: nontemporal builtins need a NATIVE clang
// vector type, not HIP_vector_type<float,4>. Stream via ext_vector f32x4.
//  - explicit software pipeline: prefetch next UNROLL float4 batch BEFORE
//    computing the current batch (no batch-boundary vmcnt drain).
//  - nontemporal loads AND stores: both streams are use-once; avoid
//    L2/L3 pollution (268MB+268MB vs 256MB L3, zero reuse).
//  - kept from R2: per-channel block, 160 B float2 table, single
//    ds_read_b64 gather (conflict-free broadcast), exact ref bin math.

#define MT_BINS 20
#define NTHREADS 256
#define PLANE_VEC 16384                 // float4 per (b,c) plane = 256*256/4
#define BPP 4                           // blocks per plane
#define CHUNK (PLANE_VEC / BPP)         // 4096 float4 per block
#define ITERS (CHUNK / NTHREADS)        // 16
#define UNROLL 4

typedef float f32x4 __attribute__((ext_vector_type(4)));

__device__ __forceinline__ float mtsilu_elem(float xk,
                                             const float2* __restrict__ swb) {
    int idx = __float2int_rd(xk * 10.0f) + (MT_BINS / 2);  // == floor(x*10)+10
    idx = idx < 0 ? 0 : (idx > MT_BINS - 1 ? MT_BINS - 1 : idx);
    float2 t = swb[idx];                                   // one ds_read_b64
    float s = __builtin_amdgcn_rcpf(1.0f + __expf(-xk));   // ~1ulp sigmoid
    return fmaf(t.x, xk, t.y) * s;
}

__device__ __forceinline__ f32x4 mtsilu_vec(f32x4 v,
                                            const float2* __restrict__ swb) {
    f32x4 o;
    o.x = mtsilu_elem(v.x, swb);
    o.y = mtsilu_elem(v.y, swb);
    o.z = mtsilu_elem(v.z, swb);
    o.w = mtsilu_elem(v.w, swb);
    return o;
}

__global__ __launch_bounds__(NTHREADS) void mtsilu_kernel(
    const f32x4* __restrict__ x,
    const float* __restrict__ weight,
    const float* __restrict__ bias,
    f32x4* __restrict__ out,
    int nvec)
{
    __shared__ float2 swb[MT_BINS];
    const int c = ((int)blockIdx.x / BPP) & 63;   // CHUNK | PLANE_VEC -> one channel/block
    if (threadIdx.x < MT_BINS) {
        swb[threadIdx.x] = make_float2(weight[c * MT_BINS + threadIdx.x],
                                       bias[c * MT_BINS + threadIdx.x]);
    }
    __syncthreads();

    const int base = (int)blockIdx.x * CHUNK + (int)threadIdx.x;

    if (base + (ITERS - 1) * NTHREADS < nvec) {
        // Fast path (whole bench shape): explicit 2-stage software pipeline.
        f32x4 cur[UNROLL];
        #pragma unroll
        for (int u = 0; u < UNROLL; ++u)
            cur[u] = __builtin_nontemporal_load(&x[base + u * NTHREADS]);

        #pragma unroll
        for (int it = 0; it < ITERS; it += UNROLL) {
            f32x4 nxt[UNROLL];
            if (it + UNROLL < ITERS) {           // compile-time resolved
                #pragma unroll
                for (int u = 0; u < UNROLL; ++u)
                    nxt[u] = __builtin_nontemporal_load(
                        &x[base + (it + UNROLL + u) * NTHREADS]);
            }
            #pragma unroll
            for (int u = 0; u < UNROLL; ++u) {
                f32x4 o = mtsilu_vec(cur[u], swb);
                __builtin_nontemporal_store(o, &out[base + (it + u) * NTHREADS]);
            }
            #pragma unroll
            for (int u = 0; u < UNROLL; ++u)
                cur[u] = nxt[u];
        }
    } else {
        // Guarded tail (unused for the bench shape: 16777216 % 4096 == 0).
        for (int it = 0; it < ITERS; ++it) {
            int j = base + it * NTHREADS;
            if (j < nvec) {
                f32x4 o = mtsilu_vec(x[j], swb);
                out[j] = o;
            }
        }
    }
}

extern "C" void kernel_launch(void* const* d_in, const int* in_sizes, int n_in,
                              void* d_out, int out_size, void* d_ws, size_t ws_size,
                              hipStream_t stream) {
    const f32x4* x      = (const f32x4*)d_in[0];
    const float* weight = (const float*)d_in[1];
    const float* bias   = (const float*)d_in[2];
    f32x4*       out    = (f32x4*)d_out;

    const int n    = in_sizes[0];        // 16*64*256*256 = 67108864 elements
    const int nvec = n / 4;              // 16777216 float4

    const int grid = (nvec + CHUNK - 1) / CHUNK;   // 4096 blocks
    mtsilu_kernel<<<grid, NTHREADS, 0, stream>>>(x, weight, bias, out, nvec);
}